// Round 15
// baseline (287.064 us; speedup 1.0000x reference)
//
#include <hip/hip_runtime.h>

typedef _Float16 half_t;
typedef int   v2i __attribute__((ext_vector_type(2)));
typedef int   v4i __attribute__((ext_vector_type(4)));
typedef float v4f __attribute__((ext_vector_type(4)));

#define OUTS 7
#define NORI 8
#define NCH  256
#define FH   128
#define FW   128
#define HW   (FH * FW)
#define NSAMP (2 * OUTS * 2 * OUTS)  // 196 = 49 bins * 4 subsamples
#define NBIN  (OUTS * OUTS)          // 49
#define WBINS 7                      // bins per wave (8 waves, starts 0,6,...,42)
#define NBKT  512                    // sort buckets: batch(1b) x morton(8b)

// ---------------- transpose [N,C,H,W] f32 -> [N,H,W,C] f16 ----------------
__global__ __launch_bounds__(256) void transpose_nchw_nhwc_h(
    const float* __restrict__ in, half_t* __restrict__ out) {
  __shared__ float tile[64][65];
  const int b  = blockIdx.z;
  const int p0 = blockIdx.x * 64;
  const int c0 = blockIdx.y * 64;
  const int tx = threadIdx.x & 63;
  const int ty = threadIdx.x >> 6;

  const float* src = in + ((size_t)b * NCH + c0) * HW + p0;
#pragma unroll
  for (int i = 0; i < 16; ++i) {
    int c = ty + i * 4;
    tile[c][tx] = src[(size_t)c * HW + tx];
  }
  __syncthreads();
  half_t* dst = out + ((size_t)b * HW + p0) * NCH + c0;
#pragma unroll
  for (int i = 0; i < 16; ++i) {
    int p = ty + i * 4;
    dst[(size_t)p * NCH + tx] = (half_t)tile[tx][p];
  }
}

// ---------------- roi spatial sort: hist -> scan -> scatter ---------------
__global__ __launch_bounds__(256) void key_hist_kernel(
    const float* __restrict__ rois, int R, int* __restrict__ hist,
    int* __restrict__ keys) {
  const int i = blockIdx.x * 256 + threadIdx.x;
  if (i >= R) return;
  const float* roi = rois + (size_t)i * 6;
  const int b  = ((int)roi[0]) & 1;
  int mx = (((int)roi[1]) >> 5) & 15;
  int my = (((int)roi[2]) >> 5) & 15;
  mx = (mx | (mx << 2)) & 0x33; mx = (mx | (mx << 1)) & 0x55;
  my = (my | (my << 2)) & 0x33; my = (my | (my << 1)) & 0x55;
  const int key = (b << 8) | mx | (my << 1);
  keys[i] = key;
  atomicAdd(&hist[key], 1);
}

__global__ __launch_bounds__(NBKT) void scan_kernel(
    const int* __restrict__ hist, int* __restrict__ cursor) {
  __shared__ int s[NBKT];
  const int t = threadIdx.x;
  const int v = hist[t];
  s[t] = v;
  __syncthreads();
  for (int off = 1; off < NBKT; off <<= 1) {
    const int add = (t >= off) ? s[t - off] : 0;
    __syncthreads();
    s[t] += add;
    __syncthreads();
  }
  cursor[t] = s[t] - v;  // exclusive prefix
}

__global__ __launch_bounds__(256) void scatter_kernel(
    const int* __restrict__ keys, int R, int* __restrict__ cursor,
    int* __restrict__ order) {
  const int i = blockIdx.x * 256 + threadIdx.x;
  if (i >= R) return;
  const int pos = atomicAdd(&cursor[keys[i]], 1);
  order[pos] = i;
}

// fma_mix: acc(f32) += w(f32) * f16 half of packed dword. lo/hi via op_sel.
#define FMALO(accv, wv, pk) \
  asm("v_fma_mix_f32 %0, %1, %2, %0 op_sel_hi:[0,1,0]" \
      : "+v"(accv) : "v"(wv), "v"(pk))
#define FMAHI(accv, wv, pk) \
  asm("v_fma_mix_f32 %0, %1, %2, %0 op_sel:[0,1,0] op_sel_hi:[0,1,0]" \
      : "+v"(accv) : "v"(wv), "v"(pk))

// ---------------- main kernel ---------------------------------------------
// Row-pair gather: sample -> 2 row-descriptors {obase, w_lo, w_hi}. One
// dwordx4 per row covers BOTH x-taps (1KB contiguous across the wave):
// lane l = half h (x0/x1) * sublane s; lane reads obase + l*16 = 8 channels
// of its tap. Per sample: 2 loads + 16 fma_mix (vs 4 loads before).
// After the loop one shfl_xor(32) merges the two tap-halves; each lane then
// holds a full 8-orientation channel group -> orientation mix is in-register
// with ZERO shuffles.
template <bool SORTED>
__global__ __launch_bounds__(512) void riroi_main(
    const half_t* __restrict__ feat, const float* __restrict__ rois,
    const int* __restrict__ order, float* __restrict__ out) {
  __shared__ v2i s_go[NSAMP];                    // 1568 B  (o_row0, o_row1)
  __shared__ v4f s_gw[NSAMP];                    // 3136 B  (wlo0,whi0,wlo1,whi1)
  __shared__ alignas(16) float s_tr[64 * NBIN];  // 12544 B

  const int t = threadIdx.x;
  const int w = t >> 6;
  const int l = t & 63;
  const int s = l & 31;   // sublane: channel group
  const int h = l >> 5;   // half: 0 = x0 tap, 1 = x1 tap
  const int b0 = w * 6;
  const int gbase = w * 24;  // first sample index of this wave's bin strip

  int r;
  if (SORTED) {
    const int bid = blockIdx.x, nwg = gridDim.x;
    const int virt = ((nwg & 7) == 0) ? ((bid & 7) * (nwg >> 3) + (bid >> 3))
                                      : bid;
    r = order[virt];
  } else {
    r = blockIdx.x;
  }

  const float* roi = rois + (size_t)r * 6;
  const float theta = roi[5];  // uniform

  // ---- in-block geometry: one sample per thread (t < 196) ----
  if (t < NSAMP) {
    const int bin = t >> 2;
    const int sub = t & 3;
    const int by = bin / OUTS, bx = bin - by * OUTS;
    const int py = by * 2 + (sub >> 1);
    const int px = bx * 2 + (sub & 1);

    const int   b  = (int)roi[0];
    const float cx = roi[1] * 0.25f;
    const float cy = roi[2] * 0.25f;
    const float rw = fmaxf(roi[3] * 0.25f, 1.0f);
    const float rh = fmaxf(roi[4] * 0.25f, 1.0f);
    const float bin_w = rw * (1.0f / OUTS);
    const float bin_h = rh * (1.0f / OUTS);
    const float ct = cosf(theta), st = sinf(theta);
    const float hbw = 0.5f * bin_w, hbh = 0.5f * bin_h;
    const float xoff = 0.25f * bin_w - 0.5f * rw;
    const float yoff = 0.25f * bin_h - 0.5f * rh;

    const float yy = (float)py * hbh + yoff;
    const float xx = (float)px * hbw + xoff;
    const float x = xx * ct + yy * st + cx;
    const float y = yy * ct - xx * st + cy;

    v2i oo = {0, 0};
    v4f ww = {0.f, 0.f, 0.f, 0.f};
    if (x > -1.0f && x < (float)FW && y > -1.0f && y < (float)FH) {
      float xc = fmaxf(x, 0.f);
      float yc = fmaxf(y, 0.f);
      int x0 = (int)xc;
      int y0 = (int)yc;
      int y1;
      float lx, ly;
      // x border: fold both taps onto pixel W-1 (hi half of row at W-2)
      int ox; float wxl, wxh;
      if (x0 >= FW - 1) { ox = FW - 2; wxl = 0.f; wxh = 1.f; }
      else              { ox = x0; lx = xc - (float)x0; wxl = 1.f - lx; wxh = lx; }
      if (y0 >= FH - 1) { y0 = FH - 1; y1 = FH - 1; ly = 0.f; }
      else              { y1 = y0 + 1; ly = yc - (float)y0; }
      const float wy0 = 1.f - ly, wy1 = ly;
      ww.x = 0.25f * wy0 * wxl; ww.y = 0.25f * wy0 * wxh;
      ww.z = 0.25f * wy1 * wxl; ww.w = 0.25f * wy1 * wxh;
      const int base = b * HW;
      oo.x = (base + y0 * FW + ox) << 9;  // 512 B per pixel
      oo.y = (base + y1 * FW + ox) << 9;
    }
    s_go[t] = oo;
    s_gw[t] = ww;
  }
  __syncthreads();

  const float indf = theta * (8.0f / 6.2831853071795862f);
  const float ind0 = floorf(indf);
  const float lmix = indf - ind0;
  const int   ind  = ((int)ind0) & 7;
  const int   m    = (8 - ind) & 7;  // T[j] = B[(m+j)&7]

  const char* fb = (const char*)feat;
  const unsigned lane16 = (unsigned)(l << 4);  // 16 B per lane

  float acc[WBINS][8];
#pragma unroll
  for (int i = 0; i < WBINS; ++i)
#pragma unroll
    for (int j = 0; j < 8; ++j) acc[i][j] = 0.f;

#define DECLSET(S) \
  v2i og##S; float wA##S, wB##S; v4i va##S, vb##S;
  DECLSET(P) DECLSET(Q)
#undef DECLSET

#define GSTAGE(S, bt) { \
  const int gi = gbase + (bt); \
  og##S = s_go[gi]; \
  const v4f wg = s_gw[gi]; \
  wA##S = h ? wg.y : wg.x; \
  wB##S = h ? wg.w : wg.z; }

#define VSTAGE(S) { \
  va##S = *(const v4i*)(fb + ((unsigned)og##S.x + lane16)); \
  vb##S = *(const v4i*)(fb + ((unsigned)og##S.y + lane16)); }

#define FROW(wv, pk, p) { \
  FMALO(acc[p][0], wv, pk.x); FMAHI(acc[p][1], wv, pk.x); \
  FMALO(acc[p][2], wv, pk.y); FMAHI(acc[p][3], wv, pk.y); \
  FMALO(acc[p][4], wv, pk.z); FMAHI(acc[p][5], wv, pk.z); \
  FMALO(acc[p][6], wv, pk.w); FMAHI(acc[p][7], wv, pk.w); }

#define FSTAGE(S, p) FROW(wA##S, va##S, p) FROW(wB##S, vb##S, p)

#define ITER(bt, CUR, NXT) { \
  if ((bt) + 1 < 28) { GSTAGE(NXT, (bt) + 1); VSTAGE(NXT); } \
  __builtin_amdgcn_s_setprio(1); \
  FSTAGE(CUR, (bt) / 4); \
  __builtin_amdgcn_s_setprio(0); }

  // prologue
  GSTAGE(P, 0) VSTAGE(P)
  // 28 samples, 2-deep rotation (all indices compile-time)
  ITER(0,  P, Q) ITER(1,  Q, P) ITER(2,  P, Q) ITER(3,  Q, P)
  ITER(4,  P, Q) ITER(5,  Q, P) ITER(6,  P, Q) ITER(7,  Q, P)
  ITER(8,  P, Q) ITER(9,  Q, P) ITER(10, P, Q) ITER(11, Q, P)
  ITER(12, P, Q) ITER(13, Q, P) ITER(14, P, Q) ITER(15, Q, P)
  ITER(16, P, Q) ITER(17, Q, P) ITER(18, P, Q) ITER(19, Q, P)
  ITER(20, P, Q) ITER(21, Q, P) ITER(22, P, Q) ITER(23, Q, P)
  ITER(24, P, Q) ITER(25, Q, P) ITER(26, P, Q) ITER(27, Q, P)

#undef ITER
#undef FSTAGE
#undef FROW
#undef VSTAGE
#undef GSTAGE

  // ---- merge tap halves: lane s and lane s+32 hold same channels ----
#pragma unroll
  for (int bb = 0; bb < WBINS; ++bb)
#pragma unroll
    for (int j = 0; j < 8; ++j)
      acc[bb][j] += __shfl_xor(acc[bb][j], 32, 64);

  // ---- orientation mix fully in-register (8-group is lane-local) ----
#define MIX_BODY(M)                                                        \
  {                                                                        \
    _Pragma("unroll")                                                      \
    for (int bb = 0; bb < WBINS; ++bb) {                                   \
      float tt[8];                                                         \
      _Pragma("unroll")                                                    \
      for (int j = 0; j < 8; ++j) {                                        \
        const float a0 = acc[bb][((M) + j) & 7];                           \
        const float a1 = acc[bb][((M) + j + 1) & 7];                       \
        tt[j] = a0 + lmix * (a1 - a0);                                     \
      }                                                                    \
      _Pragma("unroll")                                                    \
      for (int j = 0; j < 8; ++j) acc[bb][j] = tt[j];                      \
    }                                                                      \
  }
  switch (m) {
    case 0: MIX_BODY(0) break;
    case 1: MIX_BODY(1) break;
    case 2: MIX_BODY(2) break;
    case 3: MIX_BODY(3) break;
    case 4: MIX_BODY(4) break;
    case 5: MIX_BODY(5) break;
    case 6: MIX_BODY(6) break;
    case 7: MIX_BODY(7) break;
  }
#undef MIX_BODY

  // ---- 4 channel-rounds: stage [64ch][49bin] in LDS, nt-copy coalesced ----
  // Round g covers channels 64g..64g+63 = sublanes 8g..8g+7. Both halves
  // hold identical values; h=0 writes j=0..3, h=1 writes j=4..7.
#pragma unroll
  for (int g = 0; g < 4; ++g) {
    if ((s >> 3) == g) {
      const int clb = (s & 7) * 8 + h * 4;  // local channel base
#pragma unroll
      for (int bb = 0; bb < WBINS; ++bb) {
        const int bin = b0 + bb;
#pragma unroll
        for (int jj = 0; jj < 4; ++jj)
          s_tr[(clb + jj) * NBIN + bin] = acc[bb][h * 4 + jj];
      }
    }
    __syncthreads();
    const v4f* s4 = (const v4f*)s_tr;
    v4f* d4 = (v4f*)(out + (size_t)r * (NCH * NBIN) + g * (64 * NBIN));
    for (int i = t; i < 64 * NBIN / 4; i += 512)
      __builtin_nontemporal_store(s4[i], d4 + i);
    __syncthreads();
  }
}

// ---------------- tier-3 fallback: fp32 NCHW direct ----------------------
__global__ __launch_bounds__(256) void riroi_cf(
    const float* __restrict__ feat, const float* __restrict__ rois,
    float* __restrict__ out) {
  const int r = blockIdx.x;
  const int c = threadIdx.x;
  const float* roi = rois + (size_t)r * 6;
  const int   b     = (int)roi[0];
  const float cx    = roi[1] * 0.25f;
  const float cy    = roi[2] * 0.25f;
  const float rw    = fmaxf(roi[3] * 0.25f, 1.0f);
  const float rh    = fmaxf(roi[4] * 0.25f, 1.0f);
  const float theta = roi[5];
  const float bin_w = rw * (1.0f / OUTS), bin_h = rh * (1.0f / OUTS);
  const float ct = cosf(theta), st = sinf(theta);
  const float hbw = 0.5f * bin_w, hbh = 0.5f * bin_h;
  const float xoff = 0.25f * bin_w - 0.5f * rw;
  const float yoff = 0.25f * bin_h - 0.5f * rh;
  const float* fb = feat + ((size_t)b * NCH + c) * HW;
  float acc[NBIN];
#pragma unroll
  for (int i = 0; i < NBIN; ++i) acc[i] = 0.f;
  for (int py = 0; py < 2 * OUTS; ++py) {
    const float yy = (float)py * hbh + yoff;
    for (int px = 0; px < 2 * OUTS; ++px) {
      const float xx = (float)px * hbw + xoff;
      const float x = xx * ct + yy * st + cx;
      const float y = yy * ct - xx * st + cy;
      if (x > -1.0f && x < (float)FW && y > -1.0f && y < (float)FH) {
        float xc = fmaxf(x, 0.f), yc = fmaxf(y, 0.f);
        int x0 = (int)xc, y0 = (int)yc, x1, y1;
        float lx, ly;
        if (x0 >= FW - 1) { x0 = FW - 1; x1 = FW - 1; lx = 0.f; }
        else              { x1 = x0 + 1; lx = xc - (float)x0; }
        if (y0 >= FH - 1) { y0 = FH - 1; y1 = FH - 1; ly = 0.f; }
        else              { y1 = y0 + 1; ly = yc - (float)y0; }
        const float wx0 = 1.f - lx, wy0 = 1.f - ly;
        acc[(py >> 1) * OUTS + (px >> 1)] +=
            (wy0 * wx0) * fb[y0 * FW + x0] + (wy0 * lx) * fb[y0 * FW + x1]
          + (ly * wx0) * fb[y1 * FW + x0] + (ly * lx) * fb[y1 * FW + x1];
      }
    }
  }
#pragma unroll
  for (int i = 0; i < NBIN; ++i) acc[i] *= 0.25f;
  const float indf = (theta * 8.0f) / 6.2831853071795862f;
  const float ind0 = floorf(indf);
  const float l    = indf - ind0;
  const int   ind  = ((int)ind0) % NORI;
  const int   o    = c & 7;
  const int   lane = c & 63;
  const int srcLane  = (lane & 56) | ((o - ind + 8) & 7);
  const int srcLane2 = (lane & 56) | ((o - ind + 9) & 7);
  float* op = out + ((size_t)r * NCH + c) * NBIN;
#pragma unroll
  for (int i = 0; i < NBIN; ++i) {
    const float v  = acc[i];
    const float vs = __shfl(v, srcLane, 64);
    const float vp = __shfl(v, srcLane2, 64);
    op[i] = (1.f - l) * vs + l * vp;
  }
}

extern "C" void kernel_launch(void* const* d_in, const int* in_sizes, int n_in,
                              void* d_out, int out_size, void* d_ws, size_t ws_size,
                              hipStream_t stream) {
  const float* feat = (const float*)d_in[0];
  const float* rois = (const float*)d_in[1];
  float* out = (float*)d_out;
  const int R = in_sizes[1] / 6;
  const int N = in_sizes[0] / (NCH * HW);

  const size_t sort_bytes = ((size_t)(2 * NBKT + 2 * R) * 4 + 255) & ~(size_t)255;
  const size_t feat_bytes = (size_t)N * HW * NCH * sizeof(half_t);
  const int rb = (R + 255) / 256;

  if (ws_size >= sort_bytes + feat_bytes) {
    int*    hist   = (int*)d_ws;
    int*    cursor = hist + NBKT;
    int*    keys   = cursor + NBKT;
    int*    order  = keys + R;
    half_t* ft = (half_t*)((char*)d_ws + sort_bytes);

    hipMemsetAsync(hist, 0, NBKT * sizeof(int), stream);
    key_hist_kernel<<<rb, 256, 0, stream>>>(rois, R, hist, keys);
    scan_kernel<<<1, NBKT, 0, stream>>>(hist, cursor);
    scatter_kernel<<<rb, 256, 0, stream>>>(keys, R, cursor, order);

    dim3 tg(HW / 64, NCH / 64, N);
    transpose_nchw_nhwc_h<<<tg, 256, 0, stream>>>(feat, ft);
    riroi_main<true><<<R, 512, 0, stream>>>(ft, rois, order, out);
  } else if (ws_size >= feat_bytes) {
    half_t* ft = (half_t*)d_ws;
    dim3 tg(HW / 64, NCH / 64, N);
    transpose_nchw_nhwc_h<<<tg, 256, 0, stream>>>(feat, ft);
    riroi_main<false><<<R, 512, 0, stream>>>(ft, rois, nullptr, out);
  } else {
    riroi_cf<<<R, 256, 0, stream>>>(feat, rois, out);
  }
}

// Round 16
// 210.764 us; speedup vs baseline: 1.3620x; 1.3620x over previous
//
#include <hip/hip_runtime.h>

typedef _Float16 half_t;
typedef int   v2i __attribute__((ext_vector_type(2)));
typedef int   v4i __attribute__((ext_vector_type(4)));
typedef float v4f __attribute__((ext_vector_type(4)));

#define OUTS 7
#define NORI 8
#define NCH  256
#define FH   128
#define FW   128
#define HW   (FH * FW)
#define NSAMP (2 * OUTS * 2 * OUTS)  // 196 = 49 bins * 4 subsamples
#define NBIN  (OUTS * OUTS)          // 49
#define WBINS 7                      // bins per wave (8 waves, starts 0,6,...,42)
#define NBKT  512                    // sort buckets: batch(1b) x morton(8b)

// ---------------- transpose [N,C,H,W] f32 -> [N,H,W,C] f16 ----------------
__global__ __launch_bounds__(256) void transpose_nchw_nhwc_h(
    const float* __restrict__ in, half_t* __restrict__ out) {
  __shared__ float tile[64][65];
  const int b  = blockIdx.z;
  const int p0 = blockIdx.x * 64;
  const int c0 = blockIdx.y * 64;
  const int tx = threadIdx.x & 63;
  const int ty = threadIdx.x >> 6;

  const float* src = in + ((size_t)b * NCH + c0) * HW + p0;
#pragma unroll
  for (int i = 0; i < 16; ++i) {
    int c = ty + i * 4;
    tile[c][tx] = src[(size_t)c * HW + tx];
  }
  __syncthreads();
  half_t* dst = out + ((size_t)b * HW + p0) * NCH + c0;
#pragma unroll
  for (int i = 0; i < 16; ++i) {
    int p = ty + i * 4;
    dst[(size_t)p * NCH + tx] = (half_t)tile[tx][p];
  }
}

// ---------------- roi spatial sort: hist -> scan -> scatter ---------------
__global__ __launch_bounds__(256) void key_hist_kernel(
    const float* __restrict__ rois, int R, int* __restrict__ hist,
    int* __restrict__ keys) {
  const int i = blockIdx.x * 256 + threadIdx.x;
  if (i >= R) return;
  const float* roi = rois + (size_t)i * 6;
  const int b  = ((int)roi[0]) & 1;
  int mx = (((int)roi[1]) >> 5) & 15;
  int my = (((int)roi[2]) >> 5) & 15;
  mx = (mx | (mx << 2)) & 0x33; mx = (mx | (mx << 1)) & 0x55;
  my = (my | (my << 2)) & 0x33; my = (my | (my << 1)) & 0x55;
  const int key = (b << 8) | mx | (my << 1);
  keys[i] = key;
  atomicAdd(&hist[key], 1);
}

__global__ __launch_bounds__(NBKT) void scan_kernel(
    const int* __restrict__ hist, int* __restrict__ cursor) {
  __shared__ int s[NBKT];
  const int t = threadIdx.x;
  const int v = hist[t];
  s[t] = v;
  __syncthreads();
  for (int off = 1; off < NBKT; off <<= 1) {
    const int add = (t >= off) ? s[t - off] : 0;
    __syncthreads();
    s[t] += add;
    __syncthreads();
  }
  cursor[t] = s[t] - v;  // exclusive prefix
}

__global__ __launch_bounds__(256) void scatter_kernel(
    const int* __restrict__ keys, int R, int* __restrict__ cursor,
    int* __restrict__ order) {
  const int i = blockIdx.x * 256 + threadIdx.x;
  if (i >= R) return;
  const int pos = atomicAdd(&cursor[keys[i]], 1);
  order[pos] = i;
}

// fma_mix: acc(f32) += w(f32) * f16 half of packed dword. lo/hi via op_sel.
#define FMALO(accv, wv, pk) \
  asm("v_fma_mix_f32 %0, %1, %2, %0 op_sel_hi:[0,1,0]" \
      : "+v"(accv) : "v"(wv), "v"(pk))
#define FMAHI(accv, wv, pk) \
  asm("v_fma_mix_f32 %0, %1, %2, %0 op_sel:[0,1,0] op_sel_hi:[0,1,0]" \
      : "+v"(accv) : "v"(wv), "v"(pk))

// ---------------- main kernel ---------------------------------------------
// R14 structure (best known: 125 us main). In-block geometry; 8 waves; wave
// w owns bins w*6..w*6+6; lane l covers channels 4l..4l+3 (8B loads, now
// NONTEMPORAL: roi taps are mostly distinct pixels -> no L1 reuse to keep;
// skip L1 allocation to relieve TCP fill machinery). 28 batches of
// {1 Geom: 4 loads, 16 fma_mix}, 2-deep prefetch, setprio on FMAs.
template <bool SORTED>
__global__ __launch_bounds__(512) void riroi_main(
    const half_t* __restrict__ feat, const float* __restrict__ rois,
    const int* __restrict__ order, float* __restrict__ out) {
  __shared__ v4i s_geom[NSAMP * 2];              // 6272 B
  __shared__ alignas(16) float s_tr[64 * NBIN];  // 12544 B

  const int t = threadIdx.x;
  const int w = t >> 6;
  const int l = t & 63;
  const int b0 = w * 6;
  const int gbase = w * 24;  // first geom index of this wave's bin strip

  int r;
  if (SORTED) {
    const int bid = blockIdx.x, nwg = gridDim.x;
    const int virt = ((nwg & 7) == 0) ? ((bid & 7) * (nwg >> 3) + (bid >> 3))
                                      : bid;
    r = order[virt];
  } else {
    r = blockIdx.x;
  }

  const float* roi = rois + (size_t)r * 6;
  const float theta = roi[5];  // uniform

  // ---- in-block geometry: one sample per thread (t < 196) ----
  if (t < NSAMP) {
    const int bin = t >> 2;
    const int sub = t & 3;
    const int by = bin / OUTS, bx = bin - by * OUTS;
    const int py = by * 2 + (sub >> 1);
    const int px = bx * 2 + (sub & 1);

    const int   b  = (int)roi[0];
    const float cx = roi[1] * 0.25f;
    const float cy = roi[2] * 0.25f;
    const float rw = fmaxf(roi[3] * 0.25f, 1.0f);
    const float rh = fmaxf(roi[4] * 0.25f, 1.0f);
    const float bin_w = rw * (1.0f / OUTS);
    const float bin_h = rh * (1.0f / OUTS);
    const float ct = cosf(theta), st = sinf(theta);
    const float hbw = 0.5f * bin_w, hbh = 0.5f * bin_h;
    const float xoff = 0.25f * bin_w - 0.5f * rw;
    const float yoff = 0.25f * bin_h - 0.5f * rh;

    const float yy = (float)py * hbh + yoff;
    const float xx = (float)px * hbw + xoff;
    const float x = xx * ct + yy * st + cx;
    const float y = yy * ct - xx * st + cy;

    v4i oo = {0, 0, 0, 0};
    v4f ww = {0.f, 0.f, 0.f, 0.f};
    if (x > -1.0f && x < (float)FW && y > -1.0f && y < (float)FH) {
      float xc = fmaxf(x, 0.f);
      float yc = fmaxf(y, 0.f);
      int x0 = (int)xc;
      int y0 = (int)yc;
      int x1, y1;
      float lx, ly;
      if (x0 >= FW - 1) { x0 = FW - 1; x1 = FW - 1; lx = 0.f; }
      else              { x1 = x0 + 1; lx = xc - (float)x0; }
      if (y0 >= FH - 1) { y0 = FH - 1; y1 = FH - 1; ly = 0.f; }
      else              { y1 = y0 + 1; ly = yc - (float)y0; }
      const float wx0 = 1.f - lx, wy0 = 1.f - ly;
      ww.x = 0.25f * wy0 * wx0; ww.y = 0.25f * wy0 * lx;
      ww.z = 0.25f * ly  * wx0; ww.w = 0.25f * ly  * lx;
      const int base = b * HW;
      oo.x = (base + y0 * FW + x0) << 9; oo.y = (base + y0 * FW + x1) << 9;
      oo.z = (base + y1 * FW + x0) << 9; oo.w = (base + y1 * FW + x1) << 9;
    }
    s_geom[2 * t]     = oo;
    s_geom[2 * t + 1] = *(v4i*)&ww;
  }
  __syncthreads();

  const float indf = theta * (8.0f / 6.2831853071795862f);
  const float ind0 = floorf(indf);
  const float lmix = indf - ind0;
  const int   ind  = ((int)ind0) & 7;
  const int   m    = (8 - ind) & 7;  // T[j] = B[(m+j)&7]

  const char* fb = (const char*)feat;
  const unsigned lane_off = (unsigned)(l << 3);  // 8 B per lane (4 fp16 ch)

  float acc[WBINS][4];
#pragma unroll
  for (int i = 0; i < WBINS; ++i)
#pragma unroll
    for (int j = 0; j < 4; ++j) acc[i][j] = 0.f;

#define DECLSET(S) \
  v4i og##S; v4f wg##S; v2i va##S, vb##S, vc##S, vd##S;
  DECLSET(P) DECLSET(Q)
#undef DECLSET

#define GSTAGE(S, bt) { \
  const int gi = gbase + (bt); \
  og##S = s_geom[2 * gi]; wg##S = *(const v4f*)&s_geom[2 * gi + 1]; }

#define VSTAGE(S) { \
  va##S = __builtin_nontemporal_load((const v2i*)(fb + ((unsigned)og##S.x + lane_off))); \
  vb##S = __builtin_nontemporal_load((const v2i*)(fb + ((unsigned)og##S.y + lane_off))); \
  vc##S = __builtin_nontemporal_load((const v2i*)(fb + ((unsigned)og##S.z + lane_off))); \
  vd##S = __builtin_nontemporal_load((const v2i*)(fb + ((unsigned)og##S.w + lane_off))); }

#define FTAP(wv, pk, p) { \
  FMALO(acc[p][0], wv, pk.x); FMAHI(acc[p][1], wv, pk.x); \
  FMALO(acc[p][2], wv, pk.y); FMAHI(acc[p][3], wv, pk.y); }

#define FSTAGE(S, p) \
  FTAP(wg##S.x, va##S, p) FTAP(wg##S.y, vb##S, p) \
  FTAP(wg##S.z, vc##S, p) FTAP(wg##S.w, vd##S, p)

#define ITER(bt, CUR, NXT) { \
  if ((bt) + 1 < 28) { GSTAGE(NXT, (bt) + 1); VSTAGE(NXT); } \
  __builtin_amdgcn_s_setprio(1); \
  FSTAGE(CUR, (bt) / 4); \
  __builtin_amdgcn_s_setprio(0); }

  // prologue
  GSTAGE(P, 0) VSTAGE(P)
  // 28 batches, 2-deep rotation (all indices compile-time)
  ITER(0,  P, Q) ITER(1,  Q, P) ITER(2,  P, Q) ITER(3,  Q, P)
  ITER(4,  P, Q) ITER(5,  Q, P) ITER(6,  P, Q) ITER(7,  Q, P)
  ITER(8,  P, Q) ITER(9,  Q, P) ITER(10, P, Q) ITER(11, Q, P)
  ITER(12, P, Q) ITER(13, Q, P) ITER(14, P, Q) ITER(15, Q, P)
  ITER(16, P, Q) ITER(17, Q, P) ITER(18, P, Q) ITER(19, Q, P)
  ITER(20, P, Q) ITER(21, Q, P) ITER(22, P, Q) ITER(23, Q, P)
  ITER(24, P, Q) ITER(25, Q, P) ITER(26, P, Q) ITER(27, Q, P)

#undef ITER
#undef FSTAGE
#undef FTAP
#undef VSTAGE
#undef GSTAGE

  // ---- orientation mix in-register (lane pair holds the 8-group) ----
#define MIX_BODY(M)                                                        \
  {                                                                        \
    _Pragma("unroll")                                                      \
    for (int bb = 0; bb < WBINS; ++bb) {                                   \
      float B[8];                                                          \
      B[0] = acc[bb][0]; B[1] = acc[bb][1];                                \
      B[2] = acc[bb][2]; B[3] = acc[bb][3];                                \
      B[4] = __shfl_xor(acc[bb][0], 1, 64);                                \
      B[5] = __shfl_xor(acc[bb][1], 1, 64);                                \
      B[6] = __shfl_xor(acc[bb][2], 1, 64);                                \
      B[7] = __shfl_xor(acc[bb][3], 1, 64);                                \
      float tt[4];                                                         \
      _Pragma("unroll")                                                    \
      for (int j = 0; j < 4; ++j) {                                        \
        const float a0 = B[((M) + j) & 7];                                 \
        const float a1 = B[((M) + j + 1) & 7];                             \
        tt[j] = a0 + lmix * (a1 - a0);                                     \
      }                                                                    \
      acc[bb][0] = tt[0]; acc[bb][1] = tt[1];                              \
      acc[bb][2] = tt[2]; acc[bb][3] = tt[3];                              \
    }                                                                      \
  }
  switch (m) {
    case 0: MIX_BODY(0) break;
    case 1: MIX_BODY(1) break;
    case 2: MIX_BODY(2) break;
    case 3: MIX_BODY(3) break;
    case 4: MIX_BODY(4) break;
    case 5: MIX_BODY(5) break;
    case 6: MIX_BODY(6) break;
    case 7: MIX_BODY(7) break;
  }
#undef MIX_BODY

  // ---- 4 channel-rounds: stage [64ch][49bin] in LDS, nt-copy coalesced ----
#pragma unroll
  for (int g = 0; g < 4; ++g) {
    if ((l >> 4) == g) {
      const int cl = (l & 15) * 4;  // local channel base 0..60
#pragma unroll
      for (int bb = 0; bb < WBINS; ++bb) {
        const int bin = b0 + bb;
#pragma unroll
        for (int j = 0; j < 4; ++j)
          s_tr[(cl + j) * NBIN + bin] = acc[bb][j];
      }
    }
    __syncthreads();
    const v4f* s4 = (const v4f*)s_tr;
    v4f* d4 = (v4f*)(out + (size_t)r * (NCH * NBIN) + g * (64 * NBIN));
    for (int i = t; i < 64 * NBIN / 4; i += 512)
      __builtin_nontemporal_store(s4[i], d4 + i);
    __syncthreads();
  }
}

// ---------------- tier-3 fallback: fp32 NCHW direct ----------------------
__global__ __launch_bounds__(256) void riroi_cf(
    const float* __restrict__ feat, const float* __restrict__ rois,
    float* __restrict__ out) {
  const int r = blockIdx.x;
  const int c = threadIdx.x;
  const float* roi = rois + (size_t)r * 6;
  const int   b     = (int)roi[0];
  const float cx    = roi[1] * 0.25f;
  const float cy    = roi[2] * 0.25f;
  const float rw    = fmaxf(roi[3] * 0.25f, 1.0f);
  const float rh    = fmaxf(roi[4] * 0.25f, 1.0f);
  const float theta = roi[5];
  const float bin_w = rw * (1.0f / OUTS), bin_h = rh * (1.0f / OUTS);
  const float ct = cosf(theta), st = sinf(theta);
  const float hbw = 0.5f * bin_w, hbh = 0.5f * bin_h;
  const float xoff = 0.25f * bin_w - 0.5f * rw;
  const float yoff = 0.25f * bin_h - 0.5f * rh;
  const float* fb = feat + ((size_t)b * NCH + c) * HW;
  float acc[NBIN];
#pragma unroll
  for (int i = 0; i < NBIN; ++i) acc[i] = 0.f;
  for (int py = 0; py < 2 * OUTS; ++py) {
    const float yy = (float)py * hbh + yoff;
    for (int px = 0; px < 2 * OUTS; ++px) {
      const float xx = (float)px * hbw + xoff;
      const float x = xx * ct + yy * st + cx;
      const float y = yy * ct - xx * st + cy;
      if (x > -1.0f && x < (float)FW && y > -1.0f && y < (float)FH) {
        float xc = fmaxf(x, 0.f), yc = fmaxf(y, 0.f);
        int x0 = (int)xc, y0 = (int)yc, x1, y1;
        float lx, ly;
        if (x0 >= FW - 1) { x0 = FW - 1; x1 = FW - 1; lx = 0.f; }
        else              { x1 = x0 + 1; lx = xc - (float)x0; }
        if (y0 >= FH - 1) { y0 = FH - 1; y1 = FH - 1; ly = 0.f; }
        else              { y1 = y0 + 1; ly = yc - (float)y0; }
        const float wx0 = 1.f - lx, wy0 = 1.f - ly;
        acc[(py >> 1) * OUTS + (px >> 1)] +=
            (wy0 * wx0) * fb[y0 * FW + x0] + (wy0 * lx) * fb[y0 * FW + x1]
          + (ly * wx0) * fb[y1 * FW + x0] + (ly * lx) * fb[y1 * FW + x1];
      }
    }
  }
#pragma unroll
  for (int i = 0; i < NBIN; ++i) acc[i] *= 0.25f;
  const float indf = (theta * 8.0f) / 6.2831853071795862f;
  const float ind0 = floorf(indf);
  const float l    = indf - ind0;
  const int   ind  = ((int)ind0) % NORI;
  const int   o    = c & 7;
  const int   lane = c & 63;
  const int srcLane  = (lane & 56) | ((o - ind + 8) & 7);
  const int srcLane2 = (lane & 56) | ((o - ind + 9) & 7);
  float* op = out + ((size_t)r * NCH + c) * NBIN;
#pragma unroll
  for (int i = 0; i < NBIN; ++i) {
    const float v  = acc[i];
    const float vs = __shfl(v, srcLane, 64);
    const float vp = __shfl(v, srcLane2, 64);
    op[i] = (1.f - l) * vs + l * vp;
  }
}

extern "C" void kernel_launch(void* const* d_in, const int* in_sizes, int n_in,
                              void* d_out, int out_size, void* d_ws, size_t ws_size,
                              hipStream_t stream) {
  const float* feat = (const float*)d_in[0];
  const float* rois = (const float*)d_in[1];
  float* out = (float*)d_out;
  const int R = in_sizes[1] / 6;
  const int N = in_sizes[0] / (NCH * HW);

  const size_t sort_bytes = ((size_t)(2 * NBKT + 2 * R) * 4 + 255) & ~(size_t)255;
  const size_t feat_bytes = (size_t)N * HW * NCH * sizeof(half_t);
  const int rb = (R + 255) / 256;

  if (ws_size >= sort_bytes + feat_bytes) {
    int*    hist   = (int*)d_ws;
    int*    cursor = hist + NBKT;
    int*    keys   = cursor + NBKT;
    int*    order  = keys + R;
    half_t* ft = (half_t*)((char*)d_ws + sort_bytes);

    hipMemsetAsync(hist, 0, NBKT * sizeof(int), stream);
    key_hist_kernel<<<rb, 256, 0, stream>>>(rois, R, hist, keys);
    scan_kernel<<<1, NBKT, 0, stream>>>(hist, cursor);
    scatter_kernel<<<rb, 256, 0, stream>>>(keys, R, cursor, order);

    dim3 tg(HW / 64, NCH / 64, N);
    transpose_nchw_nhwc_h<<<tg, 256, 0, stream>>>(feat, ft);
    riroi_main<true><<<R, 512, 0, stream>>>(ft, rois, order, out);
  } else if (ws_size >= feat_bytes) {
    half_t* ft = (half_t*)d_ws;
    dim3 tg(HW / 64, NCH / 64, N);
    transpose_nchw_nhwc_h<<<tg, 256, 0, stream>>>(feat, ft);
    riroi_main<false><<<R, 512, 0, stream>>>(ft, rois, nullptr, out);
  } else {
    riroi_cf<<<R, 256, 0, stream>>>(feat, rois, out);
  }
}

// Round 17
// 138.281 us; speedup vs baseline: 2.0760x; 1.5242x over previous
//
#include <hip/hip_runtime.h>

typedef _Float16 half_t;
typedef int   v2i __attribute__((ext_vector_type(2)));
typedef int   v4i __attribute__((ext_vector_type(4)));
typedef float v4f __attribute__((ext_vector_type(4)));

#define OUTS 7
#define NORI 8
#define NCH  256
#define FH   128
#define FW   128
#define HW   (FH * FW)
#define NSAMP (2 * OUTS * 2 * OUTS)  // 196 = 49 bins * 4 subsamples
#define NBIN  (OUTS * OUTS)          // 49
#define WBINS 7                      // bins per wave (8 waves, starts 0,6,...,42)
#define NBKT  512                    // sort buckets: batch(1b) x morton(8b)

// ---------------- transpose [N,C,H,W] f32 -> [N,H,W,C] f16 ----------------
__global__ __launch_bounds__(256) void transpose_nchw_nhwc_h(
    const float* __restrict__ in, half_t* __restrict__ out) {
  __shared__ float tile[64][65];
  const int b  = blockIdx.z;
  const int p0 = blockIdx.x * 64;
  const int c0 = blockIdx.y * 64;
  const int tx = threadIdx.x & 63;
  const int ty = threadIdx.x >> 6;

  const float* src = in + ((size_t)b * NCH + c0) * HW + p0;
#pragma unroll
  for (int i = 0; i < 16; ++i) {
    int c = ty + i * 4;
    tile[c][tx] = src[(size_t)c * HW + tx];
  }
  __syncthreads();
  half_t* dst = out + ((size_t)b * HW + p0) * NCH + c0;
#pragma unroll
  for (int i = 0; i < 16; ++i) {
    int p = ty + i * 4;
    dst[(size_t)p * NCH + tx] = (half_t)tile[tx][p];
  }
}

// ---------------- roi spatial sort: hist -> scan -> scatter ---------------
__global__ __launch_bounds__(256) void key_hist_kernel(
    const float* __restrict__ rois, int R, int* __restrict__ hist,
    int* __restrict__ keys) {
  const int i = blockIdx.x * 256 + threadIdx.x;
  if (i >= R) return;
  const float* roi = rois + (size_t)i * 6;
  const int b  = ((int)roi[0]) & 1;
  int mx = (((int)roi[1]) >> 5) & 15;
  int my = (((int)roi[2]) >> 5) & 15;
  mx = (mx | (mx << 2)) & 0x33; mx = (mx | (mx << 1)) & 0x55;
  my = (my | (my << 2)) & 0x33; my = (my | (my << 1)) & 0x55;
  const int key = (b << 8) | mx | (my << 1);
  keys[i] = key;
  atomicAdd(&hist[key], 1);
}

__global__ __launch_bounds__(NBKT) void scan_kernel(
    const int* __restrict__ hist, int* __restrict__ cursor) {
  __shared__ int s[NBKT];
  const int t = threadIdx.x;
  const int v = hist[t];
  s[t] = v;
  __syncthreads();
  for (int off = 1; off < NBKT; off <<= 1) {
    const int add = (t >= off) ? s[t - off] : 0;
    __syncthreads();
    s[t] += add;
    __syncthreads();
  }
  cursor[t] = s[t] - v;  // exclusive prefix
}

__global__ __launch_bounds__(256) void scatter_kernel(
    const int* __restrict__ keys, int R, int* __restrict__ cursor,
    int* __restrict__ order) {
  const int i = blockIdx.x * 256 + threadIdx.x;
  if (i >= R) return;
  const int pos = atomicAdd(&cursor[keys[i]], 1);
  order[pos] = i;
}

// fma_mix: acc(f32) += w(f32) * f16 half of packed dword. lo/hi via op_sel.
#define FMALO(accv, wv, pk) \
  asm("v_fma_mix_f32 %0, %1, %2, %0 op_sel_hi:[0,1,0]" \
      : "+v"(accv) : "v"(wv), "v"(pk))
#define FMAHI(accv, wv, pk) \
  asm("v_fma_mix_f32 %0, %1, %2, %0 op_sel:[0,1,0] op_sel_hi:[0,1,0]" \
      : "+v"(accv) : "v"(wv), "v"(pk))

// ---------------- main kernel ---------------------------------------------
// R14 configuration (best known: 125 us main / 138 total). In-block geometry;
// 8 waves; wave w owns bins w*6..w*6+6; lane l covers channels 4l..4l+3 via
// plain 8B loads (NT loads evict L2 -> regression, R16). 28 batches of
// {1 Geom: 4 loads, 16 fma_mix}, 2-deep prefetch, setprio on FMAs.
template <bool SORTED>
__global__ __launch_bounds__(512) void riroi_main(
    const half_t* __restrict__ feat, const float* __restrict__ rois,
    const int* __restrict__ order, float* __restrict__ out) {
  __shared__ v4i s_geom[NSAMP * 2];              // 6272 B
  __shared__ alignas(16) float s_tr[64 * NBIN];  // 12544 B

  const int t = threadIdx.x;
  const int w = t >> 6;
  const int l = t & 63;
  const int b0 = w * 6;
  const int gbase = w * 24;  // first geom index of this wave's bin strip

  int r;
  if (SORTED) {
    const int bid = blockIdx.x, nwg = gridDim.x;
    const int virt = ((nwg & 7) == 0) ? ((bid & 7) * (nwg >> 3) + (bid >> 3))
                                      : bid;
    r = order[virt];
  } else {
    r = blockIdx.x;
  }

  const float* roi = rois + (size_t)r * 6;
  const float theta = roi[5];  // uniform

  // ---- in-block geometry: one sample per thread (t < 196) ----
  if (t < NSAMP) {
    const int bin = t >> 2;
    const int sub = t & 3;
    const int by = bin / OUTS, bx = bin - by * OUTS;
    const int py = by * 2 + (sub >> 1);
    const int px = bx * 2 + (sub & 1);

    const int   b  = (int)roi[0];
    const float cx = roi[1] * 0.25f;
    const float cy = roi[2] * 0.25f;
    const float rw = fmaxf(roi[3] * 0.25f, 1.0f);
    const float rh = fmaxf(roi[4] * 0.25f, 1.0f);
    const float bin_w = rw * (1.0f / OUTS);
    const float bin_h = rh * (1.0f / OUTS);
    const float ct = cosf(theta), st = sinf(theta);
    const float hbw = 0.5f * bin_w, hbh = 0.5f * bin_h;
    const float xoff = 0.25f * bin_w - 0.5f * rw;
    const float yoff = 0.25f * bin_h - 0.5f * rh;

    const float yy = (float)py * hbh + yoff;
    const float xx = (float)px * hbw + xoff;
    const float x = xx * ct + yy * st + cx;
    const float y = yy * ct - xx * st + cy;

    v4i oo = {0, 0, 0, 0};
    v4f ww = {0.f, 0.f, 0.f, 0.f};
    if (x > -1.0f && x < (float)FW && y > -1.0f && y < (float)FH) {
      float xc = fmaxf(x, 0.f);
      float yc = fmaxf(y, 0.f);
      int x0 = (int)xc;
      int y0 = (int)yc;
      int x1, y1;
      float lx, ly;
      if (x0 >= FW - 1) { x0 = FW - 1; x1 = FW - 1; lx = 0.f; }
      else              { x1 = x0 + 1; lx = xc - (float)x0; }
      if (y0 >= FH - 1) { y0 = FH - 1; y1 = FH - 1; ly = 0.f; }
      else              { y1 = y0 + 1; ly = yc - (float)y0; }
      const float wx0 = 1.f - lx, wy0 = 1.f - ly;
      ww.x = 0.25f * wy0 * wx0; ww.y = 0.25f * wy0 * lx;
      ww.z = 0.25f * ly  * wx0; ww.w = 0.25f * ly  * lx;
      const int base = b * HW;
      oo.x = (base + y0 * FW + x0) << 9; oo.y = (base + y0 * FW + x1) << 9;
      oo.z = (base + y1 * FW + x0) << 9; oo.w = (base + y1 * FW + x1) << 9;
    }
    s_geom[2 * t]     = oo;
    s_geom[2 * t + 1] = *(v4i*)&ww;
  }
  __syncthreads();

  const float indf = theta * (8.0f / 6.2831853071795862f);
  const float ind0 = floorf(indf);
  const float lmix = indf - ind0;
  const int   ind  = ((int)ind0) & 7;
  const int   m    = (8 - ind) & 7;  // T[j] = B[(m+j)&7]

  const char* fb = (const char*)feat;
  const unsigned lane_off = (unsigned)(l << 3);  // 8 B per lane (4 fp16 ch)

  float acc[WBINS][4];
#pragma unroll
  for (int i = 0; i < WBINS; ++i)
#pragma unroll
    for (int j = 0; j < 4; ++j) acc[i][j] = 0.f;

#define DECLSET(S) \
  v4i og##S; v4f wg##S; v2i va##S, vb##S, vc##S, vd##S;
  DECLSET(P) DECLSET(Q)
#undef DECLSET

#define GSTAGE(S, bt) { \
  const int gi = gbase + (bt); \
  og##S = s_geom[2 * gi]; wg##S = *(const v4f*)&s_geom[2 * gi + 1]; }

#define VSTAGE(S) { \
  va##S = *(const v2i*)(fb + ((unsigned)og##S.x + lane_off)); \
  vb##S = *(const v2i*)(fb + ((unsigned)og##S.y + lane_off)); \
  vc##S = *(const v2i*)(fb + ((unsigned)og##S.z + lane_off)); \
  vd##S = *(const v2i*)(fb + ((unsigned)og##S.w + lane_off)); }

#define FTAP(wv, pk, p) { \
  FMALO(acc[p][0], wv, pk.x); FMAHI(acc[p][1], wv, pk.x); \
  FMALO(acc[p][2], wv, pk.y); FMAHI(acc[p][3], wv, pk.y); }

#define FSTAGE(S, p) \
  FTAP(wg##S.x, va##S, p) FTAP(wg##S.y, vb##S, p) \
  FTAP(wg##S.z, vc##S, p) FTAP(wg##S.w, vd##S, p)

#define ITER(bt, CUR, NXT) { \
  if ((bt) + 1 < 28) { GSTAGE(NXT, (bt) + 1); VSTAGE(NXT); } \
  __builtin_amdgcn_s_setprio(1); \
  FSTAGE(CUR, (bt) / 4); \
  __builtin_amdgcn_s_setprio(0); }

  // prologue
  GSTAGE(P, 0) VSTAGE(P)
  // 28 batches, 2-deep rotation (all indices compile-time)
  ITER(0,  P, Q) ITER(1,  Q, P) ITER(2,  P, Q) ITER(3,  Q, P)
  ITER(4,  P, Q) ITER(5,  Q, P) ITER(6,  P, Q) ITER(7,  Q, P)
  ITER(8,  P, Q) ITER(9,  Q, P) ITER(10, P, Q) ITER(11, Q, P)
  ITER(12, P, Q) ITER(13, Q, P) ITER(14, P, Q) ITER(15, Q, P)
  ITER(16, P, Q) ITER(17, Q, P) ITER(18, P, Q) ITER(19, Q, P)
  ITER(20, P, Q) ITER(21, Q, P) ITER(22, P, Q) ITER(23, Q, P)
  ITER(24, P, Q) ITER(25, Q, P) ITER(26, P, Q) ITER(27, Q, P)

#undef ITER
#undef FSTAGE
#undef FTAP
#undef VSTAGE
#undef GSTAGE

  // ---- orientation mix in-register (lane pair holds the 8-group) ----
#define MIX_BODY(M)                                                        \
  {                                                                        \
    _Pragma("unroll")                                                      \
    for (int bb = 0; bb < WBINS; ++bb) {                                   \
      float B[8];                                                          \
      B[0] = acc[bb][0]; B[1] = acc[bb][1];                                \
      B[2] = acc[bb][2]; B[3] = acc[bb][3];                                \
      B[4] = __shfl_xor(acc[bb][0], 1, 64);                                \
      B[5] = __shfl_xor(acc[bb][1], 1, 64);                                \
      B[6] = __shfl_xor(acc[bb][2], 1, 64);                                \
      B[7] = __shfl_xor(acc[bb][3], 1, 64);                                \
      float tt[4];                                                         \
      _Pragma("unroll")                                                    \
      for (int j = 0; j < 4; ++j) {                                        \
        const float a0 = B[((M) + j) & 7];                                 \
        const float a1 = B[((M) + j + 1) & 7];                             \
        tt[j] = a0 + lmix * (a1 - a0);                                     \
      }                                                                    \
      acc[bb][0] = tt[0]; acc[bb][1] = tt[1];                              \
      acc[bb][2] = tt[2]; acc[bb][3] = tt[3];                              \
    }                                                                      \
  }
  switch (m) {
    case 0: MIX_BODY(0) break;
    case 1: MIX_BODY(1) break;
    case 2: MIX_BODY(2) break;
    case 3: MIX_BODY(3) break;
    case 4: MIX_BODY(4) break;
    case 5: MIX_BODY(5) break;
    case 6: MIX_BODY(6) break;
    case 7: MIX_BODY(7) break;
  }
#undef MIX_BODY

  // ---- 4 channel-rounds: stage [64ch][49bin] in LDS, nt-copy coalesced ----
#pragma unroll
  for (int g = 0; g < 4; ++g) {
    if ((l >> 4) == g) {
      const int cl = (l & 15) * 4;  // local channel base 0..60
#pragma unroll
      for (int bb = 0; bb < WBINS; ++bb) {
        const int bin = b0 + bb;
#pragma unroll
        for (int j = 0; j < 4; ++j)
          s_tr[(cl + j) * NBIN + bin] = acc[bb][j];
      }
    }
    __syncthreads();
    const v4f* s4 = (const v4f*)s_tr;
    v4f* d4 = (v4f*)(out + (size_t)r * (NCH * NBIN) + g * (64 * NBIN));
    for (int i = t; i < 64 * NBIN / 4; i += 512)
      __builtin_nontemporal_store(s4[i], d4 + i);
    __syncthreads();
  }
}

// ---------------- tier-3 fallback: fp32 NCHW direct ----------------------
__global__ __launch_bounds__(256) void riroi_cf(
    const float* __restrict__ feat, const float* __restrict__ rois,
    float* __restrict__ out) {
  const int r = blockIdx.x;
  const int c = threadIdx.x;
  const float* roi = rois + (size_t)r * 6;
  const int   b     = (int)roi[0];
  const float cx    = roi[1] * 0.25f;
  const float cy    = roi[2] * 0.25f;
  const float rw    = fmaxf(roi[3] * 0.25f, 1.0f);
  const float rh    = fmaxf(roi[4] * 0.25f, 1.0f);
  const float theta = roi[5];
  const float bin_w = rw * (1.0f / OUTS), bin_h = rh * (1.0f / OUTS);
  const float ct = cosf(theta), st = sinf(theta);
  const float hbw = 0.5f * bin_w, hbh = 0.5f * bin_h;
  const float xoff = 0.25f * bin_w - 0.5f * rw;
  const float yoff = 0.25f * bin_h - 0.5f * rh;
  const float* fb = feat + ((size_t)b * NCH + c) * HW;
  float acc[NBIN];
#pragma unroll
  for (int i = 0; i < NBIN; ++i) acc[i] = 0.f;
  for (int py = 0; py < 2 * OUTS; ++py) {
    const float yy = (float)py * hbh + yoff;
    for (int px = 0; px < 2 * OUTS; ++px) {
      const float xx = (float)px * hbw + xoff;
      const float x = xx * ct + yy * st + cx;
      const float y = yy * ct - xx * st + cy;
      if (x > -1.0f && x < (float)FW && y > -1.0f && y < (float)FH) {
        float xc = fmaxf(x, 0.f), yc = fmaxf(y, 0.f);
        int x0 = (int)xc, y0 = (int)yc, x1, y1;
        float lx, ly;
        if (x0 >= FW - 1) { x0 = FW - 1; x1 = FW - 1; lx = 0.f; }
        else              { x1 = x0 + 1; lx = xc - (float)x0; }
        if (y0 >= FH - 1) { y0 = FH - 1; y1 = FH - 1; ly = 0.f; }
        else              { y1 = y0 + 1; ly = yc - (float)y0; }
        const float wx0 = 1.f - lx, wy0 = 1.f - ly;
        acc[(py >> 1) * OUTS + (px >> 1)] +=
            (wy0 * wx0) * fb[y0 * FW + x0] + (wy0 * lx) * fb[y0 * FW + x1]
          + (ly * wx0) * fb[y1 * FW + x0] + (ly * lx) * fb[y1 * FW + x1];
      }
    }
  }
#pragma unroll
  for (int i = 0; i < NBIN; ++i) acc[i] *= 0.25f;
  const float indf = (theta * 8.0f) / 6.2831853071795862f;
  const float ind0 = floorf(indf);
  const float l    = indf - ind0;
  const int   ind  = ((int)ind0) % NORI;
  const int   o    = c & 7;
  const int   lane = c & 63;
  const int srcLane  = (lane & 56) | ((o - ind + 8) & 7);
  const int srcLane2 = (lane & 56) | ((o - ind + 9) & 7);
  float* op = out + ((size_t)r * NCH + c) * NBIN;
#pragma unroll
  for (int i = 0; i < NBIN; ++i) {
    const float v  = acc[i];
    const float vs = __shfl(v, srcLane, 64);
    const float vp = __shfl(v, srcLane2, 64);
    op[i] = (1.f - l) * vs + l * vp;
  }
}

extern "C" void kernel_launch(void* const* d_in, const int* in_sizes, int n_in,
                              void* d_out, int out_size, void* d_ws, size_t ws_size,
                              hipStream_t stream) {
  const float* feat = (const float*)d_in[0];
  const float* rois = (const float*)d_in[1];
  float* out = (float*)d_out;
  const int R = in_sizes[1] / 6;
  const int N = in_sizes[0] / (NCH * HW);

  const size_t sort_bytes = ((size_t)(2 * NBKT + 2 * R) * 4 + 255) & ~(size_t)255;
  const size_t feat_bytes = (size_t)N * HW * NCH * sizeof(half_t);
  const int rb = (R + 255) / 256;

  if (ws_size >= sort_bytes + feat_bytes) {
    int*    hist   = (int*)d_ws;
    int*    cursor = hist + NBKT;
    int*    keys   = cursor + NBKT;
    int*    order  = keys + R;
    half_t* ft = (half_t*)((char*)d_ws + sort_bytes);

    hipMemsetAsync(hist, 0, NBKT * sizeof(int), stream);
    key_hist_kernel<<<rb, 256, 0, stream>>>(rois, R, hist, keys);
    scan_kernel<<<1, NBKT, 0, stream>>>(hist, cursor);
    scatter_kernel<<<rb, 256, 0, stream>>>(keys, R, cursor, order);

    dim3 tg(HW / 64, NCH / 64, N);
    transpose_nchw_nhwc_h<<<tg, 256, 0, stream>>>(feat, ft);
    riroi_main<true><<<R, 512, 0, stream>>>(ft, rois, order, out);
  } else if (ws_size >= feat_bytes) {
    half_t* ft = (half_t*)d_ws;
    dim3 tg(HW / 64, NCH / 64, N);
    transpose_nchw_nhwc_h<<<tg, 256, 0, stream>>>(feat, ft);
    riroi_main<false><<<R, 512, 0, stream>>>(ft, rois, nullptr, out);
  } else {
    riroi_cf<<<R, 256, 0, stream>>>(feat, rois, out);
  }
}